// Round 1
// baseline (902.563 us; speedup 1.0000x reference)
//
#include <hip/hip_runtime.h>
#include <math.h>

#define BB 16
#define CC 32
#define OO 32
#define HH 256
#define WW 256
#define HW (HH * WW)

// ---------------------------------------------------------------------------
// Kernel 1: depthwise 5x5 Gaussian blur, SAME zero padding.
// Weights depend on sigma (device scalar) -> computed per thread (separable:
// g2d[i][j] = (e[i]/s) * (e[j]/s), s = sum(e), matching exp(..)/sum2d exactly
// up to fp rounding).
// ---------------------------------------------------------------------------
__global__ __launch_bounds__(256) void blur_kernel(const float* __restrict__ x,
                                                   const float* __restrict__ sigma_p,
                                                   float* __restrict__ xb) {
    int idx = blockIdx.x * 256 + threadIdx.x;   // over B*C*H*W
    int w  = idx & (WW - 1);
    int h  = (idx >> 8) & (HH - 1);
    int bc = idx >> 16;

    float sigma = sigma_p[0];
    float inv2s2 = 1.0f / (2.0f * sigma * sigma);

    float e[5], s = 0.0f;
#pragma unroll
    for (int i = 0; i < 5; ++i) {
        float d = (float)(i - 2);
        e[i] = expf(-(d * d) * inv2s2);
        s += e[i];
    }
    float inv_s = 1.0f / s;
    float wn[5];
#pragma unroll
    for (int i = 0; i < 5; ++i) wn[i] = e[i] * inv_s;

    const float* base = x + (size_t)bc * HW;
    float acc = 0.0f;
#pragma unroll
    for (int i = 0; i < 5; ++i) {
        int hy = h - 2 + i;
        if (hy >= 0 && hy < HH) {
            const float* row = base + hy * WW;
            float racc = 0.0f;
#pragma unroll
            for (int j = 0; j < 5; ++j) {
                int wx = w - 2 + j;
                if (wx >= 0 && wx < WW) racc = fmaf(wn[j], row[wx], racc);
            }
            acc = fmaf(wn[i], racc, acc);
        }
    }
    xb[idx] = acc;
}

// ---------------------------------------------------------------------------
// Kernel 2: transpose weight (O,C,3,3) -> wt[(c*9+k)*32 + o] so the mix
// kernel's inner o-loop reads contiguous, wave-uniform floats.
// ---------------------------------------------------------------------------
__global__ void wtrans_kernel(const float* __restrict__ wgt, float* __restrict__ wt) {
    int i = blockIdx.x * 256 + threadIdx.x;     // 9216 total
    if (i < OO * CC * 9) {
        int o  = i & 31;
        int ck = i >> 5;
        int c  = ck / 9;
        int k  = ck - 9 * c;
        wt[i] = wgt[(o * CC + c) * 9 + k];
    }
}

// ---------------------------------------------------------------------------
// Kernel 3: deformable sampling + channel mix.
// Offsets are spatially constant per tap:
//   py = (h - 1 + kyi) + UY[k]*sigma*6 ; px analogous.
// Bilinear corner weight = (wy_a * mask_y) * (wx_b * mask_x)  (masks folded).
// One block = one (b,h) row of 256 pixels; lane = w. acc[32] in registers.
// ---------------------------------------------------------------------------
__global__ __launch_bounds__(256) void mix_kernel(const float* __restrict__ xb,
                                                  const float* __restrict__ sigma_p,
                                                  const float* __restrict__ wt,
                                                  float* __restrict__ out) {
    const int w  = threadIdx.x;
    const int bh = blockIdx.x;
    const int h  = bh & (HH - 1);
    const int b  = bh >> 8;

    const float sigma = sigma_p[0];
    const float s6 = sigma * 6.0f;

    // unit-circle tap directions, (ky,kx) row-major over {-1,0,1}^2
    const float UY[9] = {-0.70710678f, -1.0f, -0.70710678f,
                          0.0f,         0.0f,  0.0f,
                          0.70710678f,  1.0f,  0.70710678f};
    const float UX[9] = {-0.70710678f,  0.0f,  0.70710678f,
                         -1.0f,         0.0f,  1.0f,
                         -0.70710678f,  0.0f,  0.70710678f};

    int   rof0[9], rof1[9], col0[9], col1[9];
    float wy0[9], wy1[9], wx0[9], wx1[9];

#pragma unroll
    for (int k = 0; k < 9; ++k) {
        const int kyi = k / 3;          // 0..2
        const int kxi = k - 3 * kyi;    // 0..2

        float py = (float)(h + kyi - 1) + UY[k] * s6;
        float fy = floorf(py);
        float ty = py - fy;
        int iy0 = (int)fy;
        int iy1 = iy0 + 1;
        wy0[k] = (1.0f - ty) * ((iy0 >= 0 && iy0 < HH) ? 1.0f : 0.0f);
        wy1[k] = ty          * ((iy1 >= 0 && iy1 < HH) ? 1.0f : 0.0f);
        rof0[k] = min(max(iy0, 0), HH - 1) * WW;
        rof1[k] = min(max(iy1, 0), HH - 1) * WW;

        float px = (float)(w + kxi - 1) + UX[k] * s6;
        float fx = floorf(px);
        float tx = px - fx;
        int ix0 = (int)fx;
        int ix1 = ix0 + 1;
        wx0[k] = (1.0f - tx) * ((ix0 >= 0 && ix0 < WW) ? 1.0f : 0.0f);
        wx1[k] = tx          * ((ix1 >= 0 && ix1 < WW) ? 1.0f : 0.0f);
        col0[k] = min(max(ix0, 0), WW - 1);
        col1[k] = min(max(ix1, 0), WW - 1);
    }

    float acc[OO];
#pragma unroll
    for (int o = 0; o < OO; ++o) acc[o] = 0.0f;

    const float* xbb = xb + (size_t)b * CC * HW;

    for (int c = 0; c < CC; ++c) {
        const float* xc = xbb + c * HW;
#pragma unroll
        for (int k = 0; k < 9; ++k) {
            float a00 = xc[rof0[k] + col0[k]];
            float a01 = xc[rof0[k] + col1[k]];
            float a10 = xc[rof1[k] + col0[k]];
            float a11 = xc[rof1[k] + col1[k]];
            float v = wy0[k] * fmaf(wx0[k], a00, wx1[k] * a01)
                    + wy1[k] * fmaf(wx0[k], a10, wx1[k] * a11);
            const float* wrow = wt + (c * 9 + k) * 32;   // wave-uniform, contiguous
#pragma unroll
            for (int o = 0; o < OO; ++o) acc[o] = fmaf(wrow[o], v, acc[o]);
        }
    }

    float* ob = out + (((size_t)b * OO) * HH + h) * WW + w;
#pragma unroll
    for (int o = 0; o < OO; ++o) ob[(size_t)o * HW] = acc[o];
}

// ---------------------------------------------------------------------------
extern "C" void kernel_launch(void* const* d_in, const int* in_sizes, int n_in,
                              void* d_out, int out_size, void* d_ws, size_t ws_size,
                              hipStream_t stream) {
    const float* x     = (const float*)d_in[0];
    const float* sigma = (const float*)d_in[1];
    const float* wgt   = (const float*)d_in[2];
    float* out = (float*)d_out;

    // workspace layout: [ wt : 9216 floats ][ xb : B*C*H*W floats ]
    float* wt = (float*)d_ws;
    float* xb = wt + 9216;

    blur_kernel<<<(BB * CC * HW) / 256, 256, 0, stream>>>(x, sigma, xb);
    wtrans_kernel<<<36, 256, 0, stream>>>(wgt, wt);
    mix_kernel<<<BB * HH, 256, 0, stream>>>(xb, sigma, wt, out);
}

// Round 2
// 575.215 us; speedup vs baseline: 1.5691x; 1.5691x over previous
//
#include <hip/hip_runtime.h>
#include <math.h>

#define BB 16
#define CC 32
#define OO 32
#define HH 256
#define WW 256
#define HW (HH * WW)

typedef __attribute__((ext_vector_type(8))) short bf16x8;
typedef __attribute__((ext_vector_type(4))) float f32x4;

__device__ __forceinline__ unsigned short f2bf(float f) {
    unsigned u = __float_as_uint(f);
    u += 0x7fffu + ((u >> 16) & 1u);     // round-to-nearest-even
    return (unsigned short)(u >> 16);
}

// ---------------------------------------------------------------------------
// Kernel 1: separable 5x5 Gaussian blur (weights from device sigma) fused with
// transpose to channels-last bf16: xbt[b][h][w][c].
// One block per (b,h): vertical blur into LDS [32][261], then horizontal.
// ---------------------------------------------------------------------------
__global__ __launch_bounds__(256) void blur_t_kernel(const float* __restrict__ x,
                                                     const float* __restrict__ sigma_p,
                                                     unsigned short* __restrict__ xbt) {
    __shared__ float vb[CC][261];          // stride 261 (odd) -> conflict-free
    const int t  = threadIdx.x;
    const int bh = blockIdx.x;
    const int h  = bh & (HH - 1);
    const int b  = bh >> 8;

    const float sigma = sigma_p[0];
    const float inv2s2 = 1.0f / (2.0f * sigma * sigma);
    float e[5], s = 0.0f;
#pragma unroll
    for (int i = 0; i < 5; ++i) {
        float d = (float)(i - 2);
        e[i] = expf(-(d * d) * inv2s2);
        s += e[i];
    }
    const float inv_s = 1.0f / s;
    float wn[5];
#pragma unroll
    for (int i = 0; i < 5; ++i) wn[i] = e[i] * inv_s;

    // ---- phase 1: vertical blur, columns (wx-2) for wx in [0,260) ----
    const float* xb0 = x + (size_t)b * CC * HW;
    for (int c = 0; c < CC; ++c) {
        const float* xc = xb0 + (size_t)c * HW;
        {   // wx = t, col = t-2
            const int col = t - 2;
            float acc = 0.0f;
            if (col >= 0) {                       // col <= 253 always
#pragma unroll
                for (int i = 0; i < 5; ++i) {
                    int hy = h - 2 + i;
                    if (hy >= 0 && hy < HH) acc = fmaf(wn[i], xc[hy * WW + col], acc);
                }
            }
            vb[c][t] = acc;
        }
        if (t < 4) {  // wx = 256+t, col = 254+t
            const int col = 254 + t;
            float acc = 0.0f;
            if (col < WW) {
#pragma unroll
                for (int i = 0; i < 5; ++i) {
                    int hy = h - 2 + i;
                    if (hy >= 0 && hy < HH) acc = fmaf(wn[i], xc[hy * WW + col], acc);
                }
            }
            vb[c][256 + t] = acc;
        }
    }
    __syncthreads();

    // ---- phase 2: horizontal blur + bf16 channels-last write ----
    const int c  = t & 31;
    const int wo = t >> 5;
    unsigned short* ob = xbt + (size_t)bh * (WW * CC);
#pragma unroll 4
    for (int it = 0; it < 32; ++it) {
        int w = it * 8 + wo;
        float acc = 0.0f;
#pragma unroll
        for (int j = 0; j < 5; ++j) acc = fmaf(wn[j], vb[c][w + j], acc);
        ob[w * CC + c] = f2bf(acc);
    }
}

// ---------------------------------------------------------------------------
// Kernel 2: pack weights (O,C,3,3) f32 -> exact B-fragment order, bf16.
// Fragment f = s*2+nh (s=tap, nh=o-half); lane l, elem j:
//   B[k = (l>>4)*8+j (=channel c), col = l&15 (=o within half)]
// flat index = ((f*64)+l)*8 + j.
// ---------------------------------------------------------------------------
__global__ void wtrans_kernel(const float* __restrict__ wgt, unsigned short* __restrict__ wb) {
    int i = blockIdx.x * 256 + threadIdx.x;    // 9216 total
    if (i < 18 * 64 * 8) {
        int j  = i & 7;
        int l  = (i >> 3) & 63;
        int f  = i >> 9;
        int s_ = f >> 1;
        int nh = f & 1;
        int o  = nh * 16 + (l & 15);
        int cc = ((l >> 4) << 3) + j;
        wb[i] = f2bf(wgt[(o * CC + cc) * 9 + s_]);
    }
}

// ---------------------------------------------------------------------------
// Kernel 3: deformable sample + channel mix as implicit GEMM on MFMA.
// D[16 pix x 16 out] += A[16 pix x 32 c] * B[32 c x 16 out], 9 K-steps (taps).
// Each lane builds its 8 A elems: pixel=lane&15, channels c0..c0+7, one tap ->
// one bilinear position, 4 x dwordx4 corner loads from channels-last bf16 xbt.
// ---------------------------------------------------------------------------
__global__ __launch_bounds__(256) void mix_mfma_kernel(const unsigned short* __restrict__ xbt,
                                                       const float* __restrict__ sigma_p,
                                                       const unsigned short* __restrict__ wb,
                                                       float* __restrict__ out) {
    const int lane = threadIdx.x & 63;
    const int wgid = blockIdx.x * 4 + (threadIdx.x >> 6);
    const float s6 = sigma_p[0] * 6.0f;

    // hoist B fragments (18 x 4 VGPR)
    bf16x8 bfr[18];
#pragma unroll
    for (int f = 0; f < 18; ++f)
        bfr[f] = *reinterpret_cast<const bf16x8*>(wb + ((f << 6) + lane) * 8);

    const float UY[9] = {-0.70710678f, -1.0f, -0.70710678f, 0.0f, 0.0f, 0.0f,
                          0.70710678f,  1.0f,  0.70710678f};
    const float UX[9] = {-0.70710678f, 0.0f, 0.70710678f, -1.0f, 0.0f, 1.0f,
                         -0.70710678f, 0.0f, 0.70710678f};
    const int KYI[9] = {-1, -1, -1, 0, 0, 0, 1, 1, 1};   // kyi - 1
    const int KXI[9] = {-1, 0, 1, -1, 0, 1, -1, 0, 1};   // kxi - 1

    const int mrow = lane & 15;
    const int c0   = (lane >> 4) << 3;

    for (int tt = 0; tt < 8; ++tt) {
        const int tile  = wgid * 8 + tt;           // 65536 tiles = 8192 waves * 8
        const int wbase = (tile & 15) << 4;
        const int h     = (tile >> 4) & 255;
        const int b     = tile >> 12;

        f32x4 acc0 = {0.f, 0.f, 0.f, 0.f};
        f32x4 acc1 = {0.f, 0.f, 0.f, 0.f};
        const unsigned short* xb_b = xbt + (size_t)b * (HW * CC);
        const float pxf = (float)(wbase + mrow);

#pragma unroll
        for (int s_ = 0; s_ < 9; ++s_) {
            // y (wave-uniform per tap)
            float py  = (float)(h + KYI[s_]) + UY[s_] * s6;
            float fy  = floorf(py);
            float ty  = py - fy;
            int iy0   = (int)fy, iy1 = iy0 + 1;
            float wy0 = (1.0f - ty) * ((iy0 >= 0 && iy0 < HH) ? 1.0f : 0.0f);
            float wy1 = ty          * ((iy1 >= 0 && iy1 < HH) ? 1.0f : 0.0f);
            int y0 = min(max(iy0, 0), HH - 1);
            int y1 = min(max(iy1, 0), HH - 1);
            // x (per lane)
            float px  = pxf + (float)KXI[s_] + UX[s_] * s6;
            float fx  = floorf(px);
            float tx  = px - fx;
            int ix0   = (int)fx, ix1 = ix0 + 1;
            float wx0 = (1.0f - tx) * ((ix0 >= 0 && ix0 < WW) ? 1.0f : 0.0f);
            float wx1 = tx          * ((ix1 >= 0 && ix1 < WW) ? 1.0f : 0.0f);
            int x0 = min(max(ix0, 0), WW - 1);
            int x1 = min(max(ix1, 0), WW - 1);

            const unsigned short* r0 = xb_b + (size_t)y0 * (WW * CC);
            const unsigned short* r1 = xb_b + (size_t)y1 * (WW * CC);
            uint4 a00 = *(const uint4*)(r0 + x0 * CC + c0);
            uint4 a01 = *(const uint4*)(r0 + x1 * CC + c0);
            uint4 a10 = *(const uint4*)(r1 + x0 * CC + c0);
            uint4 a11 = *(const uint4*)(r1 + x1 * CC + c0);

            const float W00 = wy0 * wx0, W01 = wy0 * wx1;
            const float W10 = wy1 * wx0, W11 = wy1 * wx1;

            unsigned q00[4] = {a00.x, a00.y, a00.z, a00.w};
            unsigned q01[4] = {a01.x, a01.y, a01.z, a01.w};
            unsigned q10[4] = {a10.x, a10.y, a10.z, a10.w};
            unsigned q11[4] = {a11.x, a11.y, a11.z, a11.w};

            bf16x8 af;
#pragma unroll
            for (int j = 0; j < 8; ++j) {
                const int wsel = j >> 1;
                float f00 = __uint_as_float((j & 1) ? (q00[wsel] & 0xffff0000u) : (q00[wsel] << 16));
                float f01 = __uint_as_float((j & 1) ? (q01[wsel] & 0xffff0000u) : (q01[wsel] << 16));
                float f10 = __uint_as_float((j & 1) ? (q10[wsel] & 0xffff0000u) : (q10[wsel] << 16));
                float f11 = __uint_as_float((j & 1) ? (q11[wsel] & 0xffff0000u) : (q11[wsel] << 16));
                float v = W00 * f00;
                v = fmaf(W01, f01, v);
                v = fmaf(W10, f10, v);
                v = fmaf(W11, f11, v);
                af[j] = (short)f2bf(v);
            }

            acc0 = __builtin_amdgcn_mfma_f32_16x16x32_bf16(af, bfr[2 * s_],     acc0, 0, 0, 0);
            acc1 = __builtin_amdgcn_mfma_f32_16x16x32_bf16(af, bfr[2 * s_ + 1], acc1, 0, 0, 0);
        }

        // D: col (=o low 4 bits) = lane&15, row (=pixel) = (lane>>4)*4 + reg
        const int prow = (lane >> 4) << 2;
        float* op = out + ((size_t)b * OO + (lane & 15)) * HW + (size_t)h * WW + wbase + prow;
        *reinterpret_cast<f32x4*>(op) = acc0;
        *reinterpret_cast<f32x4*>(op + (size_t)16 * HW) = acc1;
    }
}

// ---------------------------------------------------------------------------
extern "C" void kernel_launch(void* const* d_in, const int* in_sizes, int n_in,
                              void* d_out, int out_size, void* d_ws, size_t ws_size,
                              hipStream_t stream) {
    const float* x     = (const float*)d_in[0];
    const float* sigma = (const float*)d_in[1];
    const float* wgt   = (const float*)d_in[2];
    float* out = (float*)d_out;

    // ws layout: [ wb : 9216 bf16 (32KB reserved) ][ xbt : B*H*W*C bf16 ]
    unsigned short* wb  = (unsigned short*)d_ws;
    unsigned short* xbt = wb + 16384;

    blur_t_kernel<<<BB * HH, 256, 0, stream>>>(x, sigma, xbt);
    wtrans_kernel<<<36, 256, 0, stream>>>(wgt, wb);
    mix_mfma_kernel<<<2048, 256, 0, stream>>>(xbt, sigma, wb, out);
}

// Round 3
// 322.198 us; speedup vs baseline: 2.8013x; 1.7853x over previous
//
#include <hip/hip_runtime.h>
#include <math.h>

#define BB 16
#define CC 32
#define OO 32
#define HH 256
#define WW 256
#define HW (HH * WW)

typedef __attribute__((ext_vector_type(8))) short bf16x8;
typedef __attribute__((ext_vector_type(4))) float f32x4;
typedef __attribute__((ext_vector_type(4))) unsigned short us4;

__device__ __forceinline__ unsigned short f2bf(float f) {
    unsigned u = __float_as_uint(f);
    u += 0x7fffu + ((u >> 16) & 1u);     // round-to-nearest-even
    return (unsigned short)(u >> 16);
}

// ---------------------------------------------------------------------------
// Kernel 1: separable 5x5 Gaussian blur (weights from device sigma) fused with
// transpose to channels-last bf16: xbt[b][h][w][c].
// Block = one (b,h) row, all 32 channels.
// Phase 1: vertical blur; wave owns 8 channels, lanes load float4 col-groups
//          (coalesced), predicated over 5 rows, bf16 ushort4 stores to LDS.
// Phase 2: horizontal blur from LDS + transposed bf16 global write.
// LDS stride 268 ushorts (536 B): write-aligned 8B, reads <=2-way conflict.
// Column index map: vb[c][wx + 4], wx in [-2,258); wx OOB -> literal zero.
// ---------------------------------------------------------------------------
__global__ __launch_bounds__(256) void blur_t_kernel(const float* __restrict__ x,
                                                     const float* __restrict__ sigma_p,
                                                     unsigned short* __restrict__ xbt) {
    __shared__ __align__(16) unsigned short vb[CC][268];
    const int t  = threadIdx.x;
    const int bh = blockIdx.x;
    const int h  = bh & (HH - 1);
    const int b  = bh >> 8;

    const float sigma = sigma_p[0];
    const float inv2s2 = 1.0f / (2.0f * sigma * sigma);
    float e[5], s = 0.0f;
#pragma unroll
    for (int i = 0; i < 5; ++i) {
        float d = (float)(i - 2);
        e[i] = expf(-(d * d) * inv2s2);
        s += e[i];
    }
    const float inv_s = 1.0f / s;
    float wn[5];
#pragma unroll
    for (int i = 0; i < 5; ++i) wn[i] = e[i] * inv_s;

    // edge columns wx in {-2,-1,256,257} -> idx {2,3,260,261} are zero
    if (t < 128) {
        const int c  = t >> 2;
        const int e_ = t & 3;
        const int idx = (e_ < 2) ? (2 + e_) : (258 + e_);
        vb[c][idx] = 0;
    }

    // ---- phase 1: vertical blur, vectorized ----
    const int g  = t & 63;           // column group: cols 4g..4g+3
    const int cw = (t >> 6) * 8;     // wave-uniform channel base
    const float* xb0 = x + (size_t)b * CC * HW + 4 * g;
#pragma unroll 4
    for (int it = 0; it < 8; ++it) {
        const int c = cw + it;
        const float* xc = xb0 + (size_t)c * HW;
        float4 acc = make_float4(0.f, 0.f, 0.f, 0.f);
#pragma unroll
        for (int i = 0; i < 5; ++i) {
            const int hy = h - 2 + i;
            if (hy >= 0 && hy < HH) {
                float4 v = *reinterpret_cast<const float4*>(xc + hy * WW);
                acc.x = fmaf(wn[i], v.x, acc.x);
                acc.y = fmaf(wn[i], v.y, acc.y);
                acc.z = fmaf(wn[i], v.z, acc.z);
                acc.w = fmaf(wn[i], v.w, acc.w);
            }
        }
        us4 bv;
        bv[0] = f2bf(acc.x); bv[1] = f2bf(acc.y);
        bv[2] = f2bf(acc.z); bv[3] = f2bf(acc.w);
        *reinterpret_cast<us4*>(&vb[c][4 + 4 * g]) = bv;   // byte off 536c+8+8g, 8-aligned
    }
    __syncthreads();

    // ---- phase 2: horizontal blur + bf16 channels-last write ----
    const int c  = t & 31;
    const int wo = t >> 5;
    unsigned short* ob = xbt + (size_t)bh * (WW * CC) + c;
#pragma unroll 4
    for (int it = 0; it < 32; ++it) {
        const int w = it * 8 + wo;
        float acc = 0.0f;
#pragma unroll
        for (int j = 0; j < 5; ++j) {
            float f = __uint_as_float((unsigned)vb[c][w + 2 + j] << 16);
            acc = fmaf(wn[j], f, acc);
        }
        ob[w * CC] = f2bf(acc);      // lanes contiguous in c -> 64B segments
    }
}

// ---------------------------------------------------------------------------
// Kernel 2: pack weights (O,C,3,3) f32 -> exact B-fragment order, bf16.
// Fragment f = s*2+nh (s=tap, nh=o-half); lane l, elem j:
//   B[k = (l>>4)*8+j (=channel c), col = l&15 (=o within half)]
// ---------------------------------------------------------------------------
__global__ void wtrans_kernel(const float* __restrict__ wgt, unsigned short* __restrict__ wb) {
    int i = blockIdx.x * 256 + threadIdx.x;    // 9216 total
    if (i < 18 * 64 * 8) {
        int j  = i & 7;
        int l  = (i >> 3) & 63;
        int f  = i >> 9;
        int s_ = f >> 1;
        int nh = f & 1;
        int o  = nh * 16 + (l & 15);
        int cc = ((l >> 4) << 3) + j;
        wb[i] = f2bf(wgt[(o * CC + cc) * 9 + s_]);
    }
}

// ---------------------------------------------------------------------------
// Kernel 3: deformable sample + channel mix as implicit GEMM on MFMA.
// D[16 pix x 16 out] += A[16 pix x 32 c] * B[32 c x 16 out], 9 K-steps (taps).
// ---------------------------------------------------------------------------
__global__ __launch_bounds__(256) void mix_mfma_kernel(const unsigned short* __restrict__ xbt,
                                                       const float* __restrict__ sigma_p,
                                                       const unsigned short* __restrict__ wb,
                                                       float* __restrict__ out) {
    const int lane = threadIdx.x & 63;
    const int wgid = blockIdx.x * 4 + (threadIdx.x >> 6);
    const float s6 = sigma_p[0] * 6.0f;

    // hoist B fragments (18 x 4 VGPR)
    bf16x8 bfr[18];
#pragma unroll
    for (int f = 0; f < 18; ++f)
        bfr[f] = *reinterpret_cast<const bf16x8*>(wb + ((f << 6) + lane) * 8);

    const float UY[9] = {-0.70710678f, -1.0f, -0.70710678f, 0.0f, 0.0f, 0.0f,
                          0.70710678f,  1.0f,  0.70710678f};
    const float UX[9] = {-0.70710678f, 0.0f, 0.70710678f, -1.0f, 0.0f, 1.0f,
                         -0.70710678f, 0.0f, 0.70710678f};
    const int KYI[9] = {-1, -1, -1, 0, 0, 0, 1, 1, 1};
    const int KXI[9] = {-1, 0, 1, -1, 0, 1, -1, 0, 1};

    const int mrow = lane & 15;
    const int c0   = (lane >> 4) << 3;

    for (int tt = 0; tt < 8; ++tt) {
        const int tile  = wgid * 8 + tt;           // 65536 tiles
        const int wbase = (tile & 15) << 4;
        const int h     = (tile >> 4) & 255;
        const int b     = tile >> 12;

        f32x4 acc0 = {0.f, 0.f, 0.f, 0.f};
        f32x4 acc1 = {0.f, 0.f, 0.f, 0.f};
        const unsigned short* xb_b = xbt + (size_t)b * (HW * CC);
        const float pxf = (float)(wbase + mrow);

#pragma unroll
        for (int s_ = 0; s_ < 9; ++s_) {
            float py  = (float)(h + KYI[s_]) + UY[s_] * s6;
            float fy  = floorf(py);
            float ty  = py - fy;
            int iy0   = (int)fy, iy1 = iy0 + 1;
            float wy0 = (1.0f - ty) * ((iy0 >= 0 && iy0 < HH) ? 1.0f : 0.0f);
            float wy1 = ty          * ((iy1 >= 0 && iy1 < HH) ? 1.0f : 0.0f);
            int y0 = min(max(iy0, 0), HH - 1);
            int y1 = min(max(iy1, 0), HH - 1);
            float px  = pxf + (float)KXI[s_] + UX[s_] * s6;
            float fx  = floorf(px);
            float tx  = px - fx;
            int ix0   = (int)fx, ix1 = ix0 + 1;
            float wx0 = (1.0f - tx) * ((ix0 >= 0 && ix0 < WW) ? 1.0f : 0.0f);
            float wx1 = tx          * ((ix1 >= 0 && ix1 < WW) ? 1.0f : 0.0f);
            int x0 = min(max(ix0, 0), WW - 1);
            int x1 = min(max(ix1, 0), WW - 1);

            const unsigned short* r0 = xb_b + (size_t)y0 * (WW * CC);
            const unsigned short* r1 = xb_b + (size_t)y1 * (WW * CC);
            uint4 a00 = *(const uint4*)(r0 + x0 * CC + c0);
            uint4 a01 = *(const uint4*)(r0 + x1 * CC + c0);
            uint4 a10 = *(const uint4*)(r1 + x0 * CC + c0);
            uint4 a11 = *(const uint4*)(r1 + x1 * CC + c0);

            const float W00 = wy0 * wx0, W01 = wy0 * wx1;
            const float W10 = wy1 * wx0, W11 = wy1 * wx1;

            unsigned q00[4] = {a00.x, a00.y, a00.z, a00.w};
            unsigned q01[4] = {a01.x, a01.y, a01.z, a01.w};
            unsigned q10[4] = {a10.x, a10.y, a10.z, a10.w};
            unsigned q11[4] = {a11.x, a11.y, a11.z, a11.w};

            bf16x8 af;
#pragma unroll
            for (int j = 0; j < 8; ++j) {
                const int wsel = j >> 1;
                float f00 = __uint_as_float((j & 1) ? (q00[wsel] & 0xffff0000u) : (q00[wsel] << 16));
                float f01 = __uint_as_float((j & 1) ? (q01[wsel] & 0xffff0000u) : (q01[wsel] << 16));
                float f10 = __uint_as_float((j & 1) ? (q10[wsel] & 0xffff0000u) : (q10[wsel] << 16));
                float f11 = __uint_as_float((j & 1) ? (q11[wsel] & 0xffff0000u) : (q11[wsel] << 16));
                float v = W00 * f00;
                v = fmaf(W01, f01, v);
                v = fmaf(W10, f10, v);
                v = fmaf(W11, f11, v);
                af[j] = (short)f2bf(v);
            }

            acc0 = __builtin_amdgcn_mfma_f32_16x16x32_bf16(af, bfr[2 * s_],     acc0, 0, 0, 0);
            acc1 = __builtin_amdgcn_mfma_f32_16x16x32_bf16(af, bfr[2 * s_ + 1], acc1, 0, 0, 0);
        }

        const int prow = (lane >> 4) << 2;
        float* op = out + ((size_t)b * OO + (lane & 15)) * HW + (size_t)h * WW + wbase + prow;
        *reinterpret_cast<f32x4*>(op) = acc0;
        *reinterpret_cast<f32x4*>(op + (size_t)16 * HW) = acc1;
    }
}

// ---------------------------------------------------------------------------
extern "C" void kernel_launch(void* const* d_in, const int* in_sizes, int n_in,
                              void* d_out, int out_size, void* d_ws, size_t ws_size,
                              hipStream_t stream) {
    const float* x     = (const float*)d_in[0];
    const float* sigma = (const float*)d_in[1];
    const float* wgt   = (const float*)d_in[2];
    float* out = (float*)d_out;

    // ws layout: [ wb : 9216 bf16 (32KB reserved) ][ xbt : B*H*W*C bf16 ]
    unsigned short* wb  = (unsigned short*)d_ws;
    unsigned short* xbt = wb + 16384;

    blur_t_kernel<<<BB * HH, 256, 0, stream>>>(x, sigma, xbt);
    wtrans_kernel<<<36, 256, 0, stream>>>(wgt, wb);
    mix_mfma_kernel<<<2048, 256, 0, stream>>>(xbt, sigma, wb, out);
}

// Round 4
// 217.578 us; speedup vs baseline: 4.1482x; 1.4808x over previous
//
#include <hip/hip_runtime.h>
#include <math.h>

#define BB 16
#define CC 32
#define OO 32
#define HH 256
#define WW 256
#define HW (HH * WW)
#define PD 8
#define HP (HH + 2 * PD)      // 272
#define WP (WW + 2 * PD)      // 272

typedef __attribute__((ext_vector_type(8))) short bf16x8;
typedef __attribute__((ext_vector_type(4))) float f32x4;
typedef __attribute__((ext_vector_type(4))) unsigned short us4;
typedef __attribute__((ext_vector_type(8))) unsigned short us8;

__device__ __forceinline__ unsigned short f2bf(float f) {
    unsigned u = __float_as_uint(f);
    u += 0x7fffu + ((u >> 16) & 1u);     // round-to-nearest-even
    return (unsigned short)(u >> 16);
}

// ---------------------------------------------------------------------------
// Kernel 1: separable 5x5 Gaussian blur -> zero-PADDED channels-last bf16
//   xbt[b][y=h+PD][x=w+PD][c], halo (PD=8) zeroed by the same kernel.
// Block = one (b,h); XCD-swizzled so adjacent-h blocks share input rows in L2.
// ---------------------------------------------------------------------------
__global__ __launch_bounds__(256) void blur_t_kernel(const float* __restrict__ x,
                                                     const float* __restrict__ sigma_p,
                                                     unsigned short* __restrict__ xbt) {
    __shared__ __align__(16) unsigned short vb[CC][268];
    const int t  = threadIdx.x;
    const int bh = ((blockIdx.x & 7) << 9) + (blockIdx.x >> 3);   // 4096 blocks, chunk=512
    const int h  = bh & (HH - 1);
    const int b  = bh >> 8;

    // ---- halo zeroing (disjoint from interior writes) ----
    const us8 z8 = {0, 0, 0, 0, 0, 0, 0, 0};
    unsigned short* xb_img = xbt + (size_t)b * (HP * WP * CC);
    {   // side halo of own padded row y' = h+PD : x in [0,PD) U [PD+WW, WP)
        if (t < 64) {
            const int px = t >> 2;                 // 0..15
            const int xx = (px < PD) ? px : px + WW;
            unsigned short* dst = xb_img + ((size_t)(h + PD) * WP + xx) * CC + (t & 3) * 8;
            *reinterpret_cast<us8*>(dst) = z8;
        }
        if (h < PD) {          // full top padded row y' = h
            unsigned short* dst = xb_img + (size_t)h * WP * CC;
            for (int i = t; i < (WP * CC) / 8; i += 256)
                *reinterpret_cast<us8*>(dst + i * 8) = z8;
        }
        if (h >= HH - PD) {    // full bottom padded row y' = h + 2*PD
            unsigned short* dst = xb_img + (size_t)(h + 2 * PD) * WP * CC;
            for (int i = t; i < (WP * CC) / 8; i += 256)
                *reinterpret_cast<us8*>(dst + i * 8) = z8;
        }
    }

    const float sigma = sigma_p[0];
    const float inv2s2 = 1.0f / (2.0f * sigma * sigma);
    float e[5], s = 0.0f;
#pragma unroll
    for (int i = 0; i < 5; ++i) {
        float d = (float)(i - 2);
        e[i] = expf(-(d * d) * inv2s2);
        s += e[i];
    }
    const float inv_s = 1.0f / s;
    float wn[5];
#pragma unroll
    for (int i = 0; i < 5; ++i) wn[i] = e[i] * inv_s;

    // edge columns wx in {-2,-1,256,257} -> vb idx {2,3,260,261} are zero
    if (t < 128) {
        const int c  = t >> 2;
        const int e_ = t & 3;
        const int idx = (e_ < 2) ? (2 + e_) : (258 + e_);
        vb[c][idx] = 0;
    }

    // ---- phase 1: vertical blur, vectorized float4 ----
    const int g  = t & 63;
    const int cw = (t >> 6) * 8;
    const float* xb0 = x + (size_t)b * CC * HW + 4 * g;
#pragma unroll 4
    for (int it = 0; it < 8; ++it) {
        const int c = cw + it;
        const float* xc = xb0 + (size_t)c * HW;
        float4 acc = make_float4(0.f, 0.f, 0.f, 0.f);
#pragma unroll
        for (int i = 0; i < 5; ++i) {
            const int hy = h - 2 + i;
            if (hy >= 0 && hy < HH) {
                float4 v = *reinterpret_cast<const float4*>(xc + hy * WW);
                acc.x = fmaf(wn[i], v.x, acc.x);
                acc.y = fmaf(wn[i], v.y, acc.y);
                acc.z = fmaf(wn[i], v.z, acc.z);
                acc.w = fmaf(wn[i], v.w, acc.w);
            }
        }
        us4 bv;
        bv[0] = f2bf(acc.x); bv[1] = f2bf(acc.y);
        bv[2] = f2bf(acc.z); bv[3] = f2bf(acc.w);
        *reinterpret_cast<us4*>(&vb[c][4 + 4 * g]) = bv;
    }
    __syncthreads();

    // ---- phase 2: horizontal blur + padded channels-last bf16 write ----
    const int c  = t & 31;
    const int wo = t >> 5;
    unsigned short* ob = xb_img + ((size_t)(h + PD) * WP + PD) * CC + c;
#pragma unroll 4
    for (int it = 0; it < 32; ++it) {
        const int w = it * 8 + wo;
        float acc = 0.0f;
#pragma unroll
        for (int j = 0; j < 5; ++j) {
            float f = __uint_as_float((unsigned)vb[c][w + 2 + j] << 16);
            acc = fmaf(wn[j], f, acc);
        }
        ob[w * CC] = f2bf(acc);
    }
}

// ---------------------------------------------------------------------------
// Kernel 2 (single block): build compacted corner table.
// For each tap s: offy=UY[s]*6s, ty=frac(offy), integer shift sy=KYI+floor(offy)
// (exact: floor(h+KYI+offy) = h+KYI+floor(offy) since h,KYI are ints).
// Corner (dy,dx) weight = wy[dy]*wx[dx] is wave/pixel-uniform -> fold into B:
//   B'[entry] = W * B[tap]  (bf16). Zero-weight corners are dropped.
// meta[0]=n; meta[1+e] = element offset (Sy*WP + Sx)*CC into padded xbt.
// wb2[e][half][lane][j] bf16: B[k=(lane>>4)*8+j (=c), col=lane&15 (=o%16)].
// ---------------------------------------------------------------------------
__global__ void wtrans_kernel(const float* __restrict__ wgt,
                              const float* __restrict__ sigma_p,
                              int* __restrict__ meta,
                              unsigned short* __restrict__ wb2) {
    __shared__ int   s_tap[36];
    __shared__ float s_w[36];
    __shared__ int   s_n;
    const int t = threadIdx.x;

    if (t == 0) {
        const float UY[9] = {-0.70710678f, -1.0f, -0.70710678f, 0.0f, 0.0f, 0.0f,
                              0.70710678f,  1.0f,  0.70710678f};
        const float UX[9] = {-0.70710678f, 0.0f, 0.70710678f, -1.0f, 0.0f, 1.0f,
                             -0.70710678f, 0.0f, 0.70710678f};
        const int KYI[9] = {-1, -1, -1, 0, 0, 0, 1, 1, 1};
        const int KXI[9] = {-1, 0, 1, -1, 0, 1, -1, 0, 1};
        const float s6 = sigma_p[0] * 6.0f;
        int n = 0;
        for (int s_ = 0; s_ < 9; ++s_) {
            float offy = UY[s_] * s6, offx = UX[s_] * s6;
            float fy = floorf(offy), fx = floorf(offx);
            float ty = offy - fy,    tx = offx - fx;
            int sy = KYI[s_] + (int)fy;
            int sx = KXI[s_] + (int)fx;
            float wy[2] = {1.0f - ty, ty};
            float wx[2] = {1.0f - tx, tx};
            for (int dy = 0; dy < 2; ++dy)
                for (int dx = 0; dx < 2; ++dx) {
                    float wc = wy[dy] * wx[dx];
                    if (wc != 0.0f) {
                        s_tap[n] = s_;
                        s_w[n]   = wc;
                        meta[1 + n] = ((sy + dy) * WP + (sx + dx)) * CC;
                        ++n;
                    }
                }
        }
        meta[0] = n;
        s_n = n;
    }
    __syncthreads();

    const int n = s_n;
    for (int i = t; i < n * 1024; i += 256) {
        int j  = i & 7;
        int l  = (i >> 3) & 63;
        int nh = (i >> 9) & 1;
        int e  = i >> 10;
        int o  = nh * 16 + (l & 15);
        int c  = ((l >> 4) << 3) + j;
        wb2[i] = f2bf(s_w[e] * wgt[(o * CC + c) * 9 + s_tap[e]]);
    }
}

// ---------------------------------------------------------------------------
// Kernel 3: pure-MFMA mix. Per corner entry: raw 16B A loads (zero-padded
// image handles OOB), pre-scaled B' fragments, 2 MFMAs per tile. No interp.
// ---------------------------------------------------------------------------
__global__ __launch_bounds__(256) void mix2_kernel(const unsigned short* __restrict__ xbt,
                                                   const int* __restrict__ meta,
                                                   const unsigned short* __restrict__ wb2,
                                                   float* __restrict__ out) {
    const int lane = threadIdx.x & 63;
    const int blk  = ((blockIdx.x & 7) << 8) + (blockIdx.x >> 3);   // 2048 blocks, chunk=256
    const int wgid = blk * 4 + (threadIdx.x >> 6);
    const int mrow = lane & 15;
    const int c0   = (lane >> 4) << 3;
    const int ncorn = meta[0];

    const unsigned short* p[8];
#pragma unroll
    for (int tt = 0; tt < 8; ++tt) {
        const int tile  = wgid * 8 + tt;
        const int wbase = (tile & 15) << 4;
        const int h     = (tile >> 4) & 255;
        const int b     = tile >> 12;
        p[tt] = xbt + ((size_t)(b * HP + h + PD) * WP + (wbase + mrow + PD)) * CC + c0;
    }

    f32x4 acc[8][2];
#pragma unroll
    for (int tt = 0; tt < 8; ++tt) {
        acc[tt][0] = (f32x4){0.f, 0.f, 0.f, 0.f};
        acc[tt][1] = (f32x4){0.f, 0.f, 0.f, 0.f};
    }

    for (int e = 0; e < ncorn; ++e) {
        const int soff = meta[1 + e];
        const bf16x8 b0 = *reinterpret_cast<const bf16x8*>(wb2 + ((e * 2 + 0) * 64 + lane) * 8);
        const bf16x8 b1 = *reinterpret_cast<const bf16x8*>(wb2 + ((e * 2 + 1) * 64 + lane) * 8);
#pragma unroll
        for (int tt = 0; tt < 8; ++tt) {
            const bf16x8 a = *reinterpret_cast<const bf16x8*>(p[tt] + soff);
            acc[tt][0] = __builtin_amdgcn_mfma_f32_16x16x32_bf16(a, b0, acc[tt][0], 0, 0, 0);
            acc[tt][1] = __builtin_amdgcn_mfma_f32_16x16x32_bf16(a, b1, acc[tt][1], 0, 0, 0);
        }
    }

    // D: col(=o low4) = lane&15, row(=pixel) = (lane>>4)*4 + reg
    const int prow = (lane >> 4) << 2;
#pragma unroll
    for (int tt = 0; tt < 8; ++tt) {
        const int tile  = wgid * 8 + tt;
        const int wbase = (tile & 15) << 4;
        const int h     = (tile >> 4) & 255;
        const int b     = tile >> 12;
        float* op = out + ((size_t)b * OO + mrow) * HW + (size_t)h * WW + wbase + prow;
        *reinterpret_cast<f32x4*>(op) = acc[tt][0];
        *reinterpret_cast<f32x4*>(op + (size_t)16 * HW) = acc[tt][1];
    }
}

// ---------------------------------------------------------------------------
extern "C" void kernel_launch(void* const* d_in, const int* in_sizes, int n_in,
                              void* d_out, int out_size, void* d_ws, size_t ws_size,
                              hipStream_t stream) {
    const float* x     = (const float*)d_in[0];
    const float* sigma = (const float*)d_in[1];
    const float* wgt   = (const float*)d_in[2];
    float* out = (float*)d_out;

    // ws layout: [ meta: 64 ints ][ wb2: 36*1024 bf16 ] (128 KB reserved)
    //            [ xbt: BB*HP*WP*CC bf16 padded image ]
    int* meta           = (int*)d_ws;
    unsigned short* wb2 = (unsigned short*)((char*)d_ws + 256);
    unsigned short* xbt = (unsigned short*)((char*)d_ws + 131072);

    blur_t_kernel<<<BB * HH, 256, 0, stream>>>(x, sigma, xbt);
    wtrans_kernel<<<1, 256, 0, stream>>>(wgt, sigma, meta, wb2);
    mix2_kernel<<<2048, 256, 0, stream>>>(xbt, meta, wb2, out);
}

// Round 5
// 188.985 us; speedup vs baseline: 4.7759x; 1.1513x over previous
//
#include <hip/hip_runtime.h>
#include <math.h>

#define BB 16
#define CC 32
#define OO 32
#define HH 256
#define WW 256
#define HW (HH * WW)
#define PD 8
#define HP (HH + 2 * PD)      // 272
#define WP (WW + 2 * PD)      // 272

typedef __attribute__((ext_vector_type(8))) short bf16x8;
typedef __attribute__((ext_vector_type(4))) float f32x4;
typedef __attribute__((ext_vector_type(4))) unsigned short us4;
typedef __attribute__((ext_vector_type(8))) unsigned short us8;

__device__ __forceinline__ unsigned short f2bf(float f) {
    unsigned u = __float_as_uint(f);
    u += 0x7fffu + ((u >> 16) & 1u);     // round-to-nearest-even
    return (unsigned short)(u >> 16);
}
__device__ __forceinline__ float bf2f(unsigned short v) {
    return __uint_as_float((unsigned)v << 16);
}

// ---------------------------------------------------------------------------
// Kernel 1: 5x5 separable Gaussian blur -> zero-padded channels-last bf16
//   xbt[b][y=h+PD][x=w+PD][c].
// Block = (b, band of 4 rows): reads 8 input rows once (amplification 2x,
// was 5x). Two 16-channel passes keep LDS at 33.8 KB.
// Phase 1: vertical blur, float4 coalesced loads, us4 stores to LDS.
// Phase 2: horizontal blur from us4 LDS chunks, register sliding window.
// ---------------------------------------------------------------------------
__global__ __launch_bounds__(256) void blur_t_kernel(const float* __restrict__ x,
                                                     const float* __restrict__ sigma_p,
                                                     unsigned short* __restrict__ xbt) {
    __shared__ __align__(16) unsigned short vb[16][4][264];   // [c%16][row][col+4]
    const int t   = threadIdx.x;
    const int blk = ((blockIdx.x & 7) << 7) + (blockIdx.x >> 3);   // 1024 blocks, chunk 128
    const int band = blk & 63;
    const int b    = blk >> 6;
    const int h0   = band << 2;

    const float sigma = sigma_p[0];
    const float inv2s2 = 1.0f / (2.0f * sigma * sigma);
    float e[5], s = 0.0f;
#pragma unroll
    for (int i = 0; i < 5; ++i) {
        float d = (float)(i - 2);
        e[i] = expf(-(d * d) * inv2s2);
        s += e[i];
    }
    const float inv_s = 1.0f / s;
    float wn[5];
#pragma unroll
    for (int i = 0; i < 5; ++i) wn[i] = e[i] * inv_s;

    unsigned short* xb_img = xbt + (size_t)b * (HP * WP * CC);

    // ---- halo zeroing ----
    const us8 z8 = {0, 0, 0, 0, 0, 0, 0, 0};
    {   // side halos of own 4 padded rows: 4 rows x 16 px x 4 chunks = 256 tasks
        const int j  = t >> 6;
        const int px = (t >> 2) & 15;
        const int ch = t & 3;
        const int xx = (px < PD) ? px : px + WW;
        *reinterpret_cast<us8*>(xb_img + ((size_t)(h0 + PD + j) * WP + xx) * CC + ch * 8) = z8;
    }
    if (h0 < PD) {             // bands 0,1: zero full padded rows y = h0..h0+3
#pragma unroll
        for (int j2 = 0; j2 < 4; ++j2) {
            unsigned short* dst = xb_img + (size_t)(h0 + j2) * WP * CC;
            for (int i = t; i < (WP * CC) / 8; i += 256)
                *reinterpret_cast<us8*>(dst + i * 8) = z8;
        }
    }
    if (h0 + 4 > HH - PD) {    // bands 62,63: rows y = h0+j+2*PD
#pragma unroll
        for (int j2 = 0; j2 < 4; ++j2) {
            unsigned short* dst = xb_img + (size_t)(h0 + j2 + 2 * PD) * WP * CC;
            for (int i = t; i < (WP * CC) / 8; i += 256)
                *reinterpret_cast<us8*>(dst + i * 8) = z8;
        }
    }

    const int g  = t & 63;          // column group (4 px)
    const int cs = t >> 6;          // wave -> channel sub-index

#pragma unroll
    for (int pass = 0; pass < 2; ++pass) {
        if (pass) __syncthreads();  // protect vb reuse

        // edge zero cols {-2,-1,256,257} -> idx {2,3,260,261}: 16c*4j*4 = 256 tasks
        {
            const int c15 = t >> 4;
            const int j   = (t >> 2) & 3;
            const int e_  = t & 3;
            const int idx = (e_ < 2) ? (2 + e_) : (258 + e_);
            vb[c15][j][idx] = 0;
        }

        // ---- phase 1: vertical blur over 8 input rows -> 4 outputs ----
#pragma unroll
        for (int it = 0; it < 4; ++it) {
            const int c = (pass << 4) + (it << 2) + cs;
            const float* xc = x + ((size_t)(b * CC + c) * HH) * WW + 4 * g;
            float4 v[8];
#pragma unroll
            for (int k = 0; k < 8; ++k) {
                const int r = h0 - 2 + k;
                v[k] = (r >= 0 && r < HH) ? *reinterpret_cast<const float4*>(xc + r * WW)
                                          : make_float4(0.f, 0.f, 0.f, 0.f);
            }
#pragma unroll
            for (int j = 0; j < 4; ++j) {
                float4 a = make_float4(0.f, 0.f, 0.f, 0.f);
#pragma unroll
                for (int i = 0; i < 5; ++i) {
                    a.x = fmaf(wn[i], v[j + i].x, a.x);
                    a.y = fmaf(wn[i], v[j + i].y, a.y);
                    a.z = fmaf(wn[i], v[j + i].z, a.z);
                    a.w = fmaf(wn[i], v[j + i].w, a.w);
                }
                us4 bv;
                bv[0] = f2bf(a.x); bv[1] = f2bf(a.y);
                bv[2] = f2bf(a.z); bv[3] = f2bf(a.w);
                *reinterpret_cast<us4*>(&vb[c & 15][j][4 + 4 * g]) = bv;  // banks 2g: free
            }
        }
        __syncthreads();

        // ---- phase 2: horizontal blur, 16 contiguous px per thread ----
        const int c15 = t & 15;
        const int c   = (pass << 4) + c15;
        const int T   = t >> 4;          // px block [16T, 16T+16)
#pragma unroll
        for (int j = 0; j < 4; ++j) {
            us4 ch[6];
#pragma unroll
            for (int k = 0; k < 6; ++k)
                ch[k] = *reinterpret_cast<const us4*>(&vb[c15][j][16 * T + 4 * k]);
            float val[24];
#pragma unroll
            for (int q = 0; q < 24; ++q) val[q] = bf2f(ch[q >> 2][q & 3]);
            unsigned short* ob = xb_img + ((size_t)(h0 + PD + j) * WP + PD + 16 * T) * CC + c;
#pragma unroll
            for (int d = 0; d < 16; ++d) {
                float a = 0.0f;
#pragma unroll
                for (int i = 0; i < 5; ++i) a = fmaf(wn[i], val[d + 2 + i], a);
                ob[d * CC] = f2bf(a);
            }
        }
    }
}

// ---------------------------------------------------------------------------
// Kernel 2: corner table + pre-scaled B fragments. Every block recomputes the
// (cheap, deterministic) corner scan; block e fills entry e's 1024 bf16.
// meta[0]=n; meta[1+e] = element offset (Sy*WP+Sx)*CC into padded xbt.
// ---------------------------------------------------------------------------
__global__ void wtrans_kernel(const float* __restrict__ wgt,
                              const float* __restrict__ sigma_p,
                              int* __restrict__ meta,
                              unsigned short* __restrict__ wb2) {
    __shared__ int   s_tap[36];
    __shared__ float s_w[36];
    __shared__ int   s_n;
    const int t = threadIdx.x;

    if (t == 0) {
        const float UY[9] = {-0.70710678f, -1.0f, -0.70710678f, 0.0f, 0.0f, 0.0f,
                              0.70710678f,  1.0f,  0.70710678f};
        const float UX[9] = {-0.70710678f, 0.0f, 0.70710678f, -1.0f, 0.0f, 1.0f,
                             -0.70710678f, 0.0f, 0.70710678f};
        const int KYI[9] = {-1, -1, -1, 0, 0, 0, 1, 1, 1};
        const int KXI[9] = {-1, 0, 1, -1, 0, 1, -1, 0, 1};
        const float s6 = sigma_p[0] * 6.0f;
        int n = 0;
        for (int s_ = 0; s_ < 9; ++s_) {
            float offy = UY[s_] * s6, offx = UX[s_] * s6;
            float fy = floorf(offy), fx = floorf(offx);
            float ty = offy - fy,    tx = offx - fx;
            int sy = KYI[s_] + (int)fy;
            int sx = KXI[s_] + (int)fx;
            float wy[2] = {1.0f - ty, ty};
            float wx[2] = {1.0f - tx, tx};
            for (int dy = 0; dy < 2; ++dy)
                for (int dx = 0; dx < 2; ++dx) {
                    float wc = wy[dy] * wx[dx];
                    if (wc != 0.0f) {
                        s_tap[n] = s_;
                        s_w[n]   = wc;
                        if (blockIdx.x == 0) meta[1 + n] = ((sy + dy) * WP + (sx + dx)) * CC;
                        ++n;
                    }
                }
        }
        if (blockIdx.x == 0) meta[0] = n;
        s_n = n;
    }
    __syncthreads();

    const int e = blockIdx.x;
    if (e >= s_n) return;
    for (int i = t; i < 1024; i += 256) {
        int j  = i & 7;
        int l  = (i >> 3) & 63;
        int nh = (i >> 9) & 1;
        int o  = nh * 16 + (l & 15);
        int c  = ((l >> 4) << 3) + j;
        wb2[e * 1024 + i] = f2bf(s_w[e] * wgt[(o * CC + c) * 9 + s_tap[e]]);
    }
}

// ---------------------------------------------------------------------------
// Kernel 3: pure-MFMA mix. Block = one output row (b,h); wave = 64 px
// (4 MFMA tiles). Row base is SGPR (blockIdx-derived), per-corner offset is a
// wave-uniform s_load -> A loads are [saddr + fixed voffset + imm], minimal
// VALU. acc = 32 VGPRs; launch_bounds(256,8) targets 8 waves/SIMD.
// ---------------------------------------------------------------------------
__global__ __launch_bounds__(256, 8) void mix2_kernel(const unsigned short* __restrict__ xbt,
                                                      const int* __restrict__ meta,
                                                      const unsigned short* __restrict__ wb2,
                                                      float* __restrict__ out) {
    const int t    = threadIdx.x;
    const int lane = t & 63;
    const int bh   = ((blockIdx.x & 7) << 9) + (blockIdx.x >> 3);  // 4096 blocks, chunk 512
    const int h    = bh & 255;
    const int b    = bh >> 8;
    const int mrow = lane & 15;                 // A-row = pixel-in-tile
    const int c0   = (lane >> 4) << 3;          // A-cols = channel group
    const int wv   = t >> 6;                    // wave -> px [wv*64, wv*64+64)
    const int ncorn = meta[0];

    const unsigned short* rowp = xbt + ((size_t)(b * HP + h + PD) * WP + PD) * CC;  // SGPR
    const int loff = (wv * 64 + mrow) * CC + c0;                                    // VGPR const

    f32x4 acc[4][2];
#pragma unroll
    for (int tt = 0; tt < 4; ++tt) {
        acc[tt][0] = (f32x4){0.f, 0.f, 0.f, 0.f};
        acc[tt][1] = (f32x4){0.f, 0.f, 0.f, 0.f};
    }

    for (int e = 0; e < ncorn; ++e) {
        const int soff = meta[1 + e];                       // wave-uniform s_load
        const bf16x8 b0 = *reinterpret_cast<const bf16x8*>(wb2 + ((e * 2 + 0) * 64 + lane) * 8);
        const bf16x8 b1 = *reinterpret_cast<const bf16x8*>(wb2 + ((e * 2 + 1) * 64 + lane) * 8);
        const unsigned short* pe = rowp + soff;             // scalar add
#pragma unroll
        for (int tt = 0; tt < 4; ++tt) {
            const bf16x8 a = *reinterpret_cast<const bf16x8*>(pe + loff + tt * 512);  // imm offset
            acc[tt][0] = __builtin_amdgcn_mfma_f32_16x16x32_bf16(a, b0, acc[tt][0], 0, 0, 0);
            acc[tt][1] = __builtin_amdgcn_mfma_f32_16x16x32_bf16(a, b1, acc[tt][1], 0, 0, 0);
        }
    }

    // D: out channel = lane&15 (+16 for acc1), pixel = wv*64 + tt*16 + (lane>>4)*4 + reg
    const int prow = (lane >> 4) << 2;
    float* op0 = out + ((size_t)b * OO + (lane & 15)) * HW + (size_t)h * WW + wv * 64 + prow;
#pragma unroll
    for (int tt = 0; tt < 4; ++tt) {
        *reinterpret_cast<f32x4*>(op0 + tt * 16) = acc[tt][0];
        *reinterpret_cast<f32x4*>(op0 + tt * 16 + (size_t)16 * HW) = acc[tt][1];
    }
}

// ---------------------------------------------------------------------------
extern "C" void kernel_launch(void* const* d_in, const int* in_sizes, int n_in,
                              void* d_out, int out_size, void* d_ws, size_t ws_size,
                              hipStream_t stream) {
    const float* x     = (const float*)d_in[0];
    const float* sigma = (const float*)d_in[1];
    const float* wgt   = (const float*)d_in[2];
    float* out = (float*)d_out;

    // ws layout: [ meta: 64 ints ][ wb2: 36*1024 bf16 ] (128 KB reserved)
    //            [ xbt: BB*HP*WP*CC bf16 padded image ]
    int* meta           = (int*)d_ws;
    unsigned short* wb2 = (unsigned short*)((char*)d_ws + 256);
    unsigned short* xbt = (unsigned short*)((char*)d_ws + 131072);

    wtrans_kernel<<<36, 256, 0, stream>>>(wgt, sigma, meta, wb2);
    blur_t_kernel<<<BB * 64, 256, 0, stream>>>(x, sigma, xbt);
    mix2_kernel<<<BB * HH, 256, 0, stream>>>(xbt, meta, wb2, out);
}

// Round 6
// 184.485 us; speedup vs baseline: 4.8924x; 1.0244x over previous
//
#include <hip/hip_runtime.h>
#include <math.h>

#define BB 16
#define CC 32
#define OO 32
#define HH 256
#define WW 256
#define HW (HH * WW)
#define PD 8
#define HP (HH + 2 * PD)      // 272
#define WP (WW + 2 * PD)      // 272

typedef __attribute__((ext_vector_type(8))) short bf16x8;
typedef __attribute__((ext_vector_type(4))) float f32x4;
typedef __attribute__((ext_vector_type(4))) unsigned short us4;
typedef __attribute__((ext_vector_type(8))) unsigned short us8;

__device__ __forceinline__ unsigned short f2bf(float f) {
    unsigned u = __float_as_uint(f);
    u += 0x7fffu + ((u >> 16) & 1u);     // round-to-nearest-even
    return (unsigned short)(u >> 16);
}
__device__ __forceinline__ float bf2f(unsigned short v) {
    return __uint_as_float((unsigned)v << 16);
}

// ---------------------------------------------------------------------------
// Kernel 1: 5x5 separable Gaussian blur -> zero-padded channels-last bf16
//   xbt[b][y=h+PD][x=w+PD][c].  (unchanged from R5)
// ---------------------------------------------------------------------------
__global__ __launch_bounds__(256) void blur_t_kernel(const float* __restrict__ x,
                                                     const float* __restrict__ sigma_p,
                                                     unsigned short* __restrict__ xbt) {
    __shared__ __align__(16) unsigned short vb[16][4][264];   // [c%16][row][col+4]
    const int t   = threadIdx.x;
    const int blk = ((blockIdx.x & 7) << 7) + (blockIdx.x >> 3);   // 1024 blocks, chunk 128
    const int band = blk & 63;
    const int b    = blk >> 6;
    const int h0   = band << 2;

    const float sigma = sigma_p[0];
    const float inv2s2 = 1.0f / (2.0f * sigma * sigma);
    float e[5], s = 0.0f;
#pragma unroll
    for (int i = 0; i < 5; ++i) {
        float d = (float)(i - 2);
        e[i] = expf(-(d * d) * inv2s2);
        s += e[i];
    }
    const float inv_s = 1.0f / s;
    float wn[5];
#pragma unroll
    for (int i = 0; i < 5; ++i) wn[i] = e[i] * inv_s;

    unsigned short* xb_img = xbt + (size_t)b * (HP * WP * CC);

    // ---- halo zeroing ----
    const us8 z8 = {0, 0, 0, 0, 0, 0, 0, 0};
    {
        const int j  = t >> 6;
        const int px = (t >> 2) & 15;
        const int ch = t & 3;
        const int xx = (px < PD) ? px : px + WW;
        *reinterpret_cast<us8*>(xb_img + ((size_t)(h0 + PD + j) * WP + xx) * CC + ch * 8) = z8;
    }
    if (h0 < PD) {
#pragma unroll
        for (int j2 = 0; j2 < 4; ++j2) {
            unsigned short* dst = xb_img + (size_t)(h0 + j2) * WP * CC;
            for (int i = t; i < (WP * CC) / 8; i += 256)
                *reinterpret_cast<us8*>(dst + i * 8) = z8;
        }
    }
    if (h0 + 4 > HH - PD) {
#pragma unroll
        for (int j2 = 0; j2 < 4; ++j2) {
            unsigned short* dst = xb_img + (size_t)(h0 + j2 + 2 * PD) * WP * CC;
            for (int i = t; i < (WP * CC) / 8; i += 256)
                *reinterpret_cast<us8*>(dst + i * 8) = z8;
        }
    }

    const int g  = t & 63;
    const int cs = t >> 6;

#pragma unroll
    for (int pass = 0; pass < 2; ++pass) {
        if (pass) __syncthreads();

        {
            const int c15 = t >> 4;
            const int j   = (t >> 2) & 3;
            const int e_  = t & 3;
            const int idx = (e_ < 2) ? (2 + e_) : (258 + e_);
            vb[c15][j][idx] = 0;
        }

#pragma unroll
        for (int it = 0; it < 4; ++it) {
            const int c = (pass << 4) + (it << 2) + cs;
            const float* xc = x + ((size_t)(b * CC + c) * HH) * WW + 4 * g;
            float4 v[8];
#pragma unroll
            for (int k = 0; k < 8; ++k) {
                const int r = h0 - 2 + k;
                v[k] = (r >= 0 && r < HH) ? *reinterpret_cast<const float4*>(xc + r * WW)
                                          : make_float4(0.f, 0.f, 0.f, 0.f);
            }
#pragma unroll
            for (int j = 0; j < 4; ++j) {
                float4 a = make_float4(0.f, 0.f, 0.f, 0.f);
#pragma unroll
                for (int i = 0; i < 5; ++i) {
                    a.x = fmaf(wn[i], v[j + i].x, a.x);
                    a.y = fmaf(wn[i], v[j + i].y, a.y);
                    a.z = fmaf(wn[i], v[j + i].z, a.z);
                    a.w = fmaf(wn[i], v[j + i].w, a.w);
                }
                us4 bv;
                bv[0] = f2bf(a.x); bv[1] = f2bf(a.y);
                bv[2] = f2bf(a.z); bv[3] = f2bf(a.w);
                *reinterpret_cast<us4*>(&vb[c & 15][j][4 + 4 * g]) = bv;
            }
        }
        __syncthreads();

        const int c15 = t & 15;
        const int c   = (pass << 4) + c15;
        const int T   = t >> 4;
#pragma unroll
        for (int j = 0; j < 4; ++j) {
            us4 ch[6];
#pragma unroll
            for (int k = 0; k < 6; ++k)
                ch[k] = *reinterpret_cast<const us4*>(&vb[c15][j][16 * T + 4 * k]);
            float val[24];
#pragma unroll
            for (int q = 0; q < 24; ++q) val[q] = bf2f(ch[q >> 2][q & 3]);
            unsigned short* ob = xb_img + ((size_t)(h0 + PD + j) * WP + PD + 16 * T) * CC + c;
#pragma unroll
            for (int d = 0; d < 16; ++d) {
                float a = 0.0f;
#pragma unroll
                for (int i = 0; i < 5; ++i) a = fmaf(wn[i], val[d + 2 + i], a);
                ob[d * CC] = f2bf(a);
            }
        }
    }
}

// ---------------------------------------------------------------------------
// Kernel 2: corner table (SORTED by image offset => row-major locality) +
// pre-scaled B fragments. Every block recomputes the deterministic scan+sort;
// block e fills entry e's 1024 bf16.
// ---------------------------------------------------------------------------
__global__ void wtrans_kernel(const float* __restrict__ wgt,
                              const float* __restrict__ sigma_p,
                              int* __restrict__ meta,
                              unsigned short* __restrict__ wb2) {
    __shared__ int   s_tap[36];
    __shared__ float s_w[36];
    __shared__ int   s_soff[36];
    __shared__ int   s_n;
    const int t = threadIdx.x;

    if (t == 0) {
        const float UY[9] = {-0.70710678f, -1.0f, -0.70710678f, 0.0f, 0.0f, 0.0f,
                              0.70710678f,  1.0f,  0.70710678f};
        const float UX[9] = {-0.70710678f, 0.0f, 0.70710678f, -1.0f, 0.0f, 1.0f,
                             -0.70710678f, 0.0f, 0.70710678f};
        const int KYI[9] = {-1, -1, -1, 0, 0, 0, 1, 1, 1};
        const int KXI[9] = {-1, 0, 1, -1, 0, 1, -1, 0, 1};
        const float s6 = sigma_p[0] * 6.0f;
        int n = 0;
        for (int s_ = 0; s_ < 9; ++s_) {
            float offy = UY[s_] * s6, offx = UX[s_] * s6;
            float fy = floorf(offy), fx = floorf(offx);
            float ty = offy - fy,    tx = offx - fx;
            int sy = KYI[s_] + (int)fy;
            int sx = KXI[s_] + (int)fx;
            float wy[2] = {1.0f - ty, ty};
            float wx[2] = {1.0f - tx, tx};
            for (int dy = 0; dy < 2; ++dy)
                for (int dx = 0; dx < 2; ++dx) {
                    float wc = wy[dy] * wx[dx];
                    if (wc != 0.0f) {
                        s_tap[n]  = s_;
                        s_w[n]    = wc;
                        s_soff[n] = ((sy + dy) * WP + (sx + dx)) * CC;
                        ++n;
                    }
                }
        }
        // insertion sort by soff (== row-major (Sy,Sx) order)
        for (int i = 1; i < n; ++i) {
            int ks = s_soff[i]; int kt = s_tap[i]; float kw = s_w[i];
            int j = i - 1;
            while (j >= 0 && s_soff[j] > ks) {
                s_soff[j + 1] = s_soff[j]; s_tap[j + 1] = s_tap[j]; s_w[j + 1] = s_w[j];
                --j;
            }
            s_soff[j + 1] = ks; s_tap[j + 1] = kt; s_w[j + 1] = kw;
        }
        if (blockIdx.x == 0) {
            meta[0] = n;
            for (int i = 0; i < n; ++i) meta[1 + i] = s_soff[i];
        }
        s_n = n;
    }
    __syncthreads();

    const int e = blockIdx.x;
    if (e >= s_n) return;
    for (int i = t; i < 1024; i += 256) {
        int j  = i & 7;
        int l  = (i >> 3) & 63;
        int nh = (i >> 9) & 1;
        int o  = nh * 16 + (l & 15);
        int c  = ((l >> 4) << 3) + j;
        wb2[e * 1024 + i] = f2bf(s_w[e] * wgt[(o * CC + c) * 9 + s_tap[e]]);
    }
}

// ---------------------------------------------------------------------------
// Kernel 3: pure-MFMA mix, cache-traffic-optimized.
// Block = 4 waves = 2 rows x 256 px; wave = 128 px = 8 M-tiles (B amortized
// over 8 A-loads). First 16 B-entries staged in LDS (32 KB) -> B rides the
// LDS pipe, off L1. Corner entries sorted by row => consecutive e's reuse the
// same image row in L1. Output via nontemporal stores (don't evict xbt L2).
// ---------------------------------------------------------------------------
__global__ __launch_bounds__(256) void mix3_kernel(const unsigned short* __restrict__ xbt,
                                                   const int* __restrict__ meta,
                                                   const unsigned short* __restrict__ wb2,
                                                   float* __restrict__ out) {
    __shared__ us8 bs8[16 * 128];            // 16 entries x 1024 bf16 = 32 KB
    const int t    = threadIdx.x;
    const int lane = t & 63;
    const int wv   = t >> 6;
    const int bh2  = ((blockIdx.x & 7) << 8) + (blockIdx.x >> 3);  // 2048 blocks, chunk 256
    const int b    = bh2 >> 7;
    const int h    = ((bh2 & 127) << 1) + (wv >> 1);
    const int xseg = (wv & 1) << 7;          // 0 or 128
    const int mrow = lane & 15;
    const int c0   = (lane >> 4) << 3;
    const int ncorn = meta[0];
    const int nl    = min(ncorn, 16);

    // stage B entries 0..nl-1 into LDS
    for (int i = t; i < nl * 128; i += 256)
        bs8[i] = reinterpret_cast<const us8*>(wb2)[i];
    __syncthreads();

    const unsigned short* rowp = xbt + ((size_t)(b * HP + h + PD) * WP + PD) * CC;
    const int loff = (xseg + mrow) * CC + c0;

    f32x4 acc[8][2];
#pragma unroll
    for (int tt = 0; tt < 8; ++tt) {
        acc[tt][0] = (f32x4){0.f, 0.f, 0.f, 0.f};
        acc[tt][1] = (f32x4){0.f, 0.f, 0.f, 0.f};
    }

    const unsigned short* bsp = reinterpret_cast<const unsigned short*>(bs8);
    for (int e = 0; e < ncorn; ++e) {
        const int soff = meta[1 + e];                        // wave-uniform s_load
        bf16x8 b0, b1;
        if (e < nl) {
            b0 = *reinterpret_cast<const bf16x8*>(bsp + (e * 128 + lane) * 8);
            b1 = *reinterpret_cast<const bf16x8*>(bsp + (e * 128 + 64 + lane) * 8);
        } else {
            b0 = *reinterpret_cast<const bf16x8*>(wb2 + ((e * 2 + 0) * 64 + lane) * 8);
            b1 = *reinterpret_cast<const bf16x8*>(wb2 + ((e * 2 + 1) * 64 + lane) * 8);
        }
        const unsigned short* pe = rowp + soff + loff;
#pragma unroll
        for (int tt = 0; tt < 8; ++tt) {
            const bf16x8 a = *reinterpret_cast<const bf16x8*>(pe + tt * 512);
            acc[tt][0] = __builtin_amdgcn_mfma_f32_16x16x32_bf16(a, b0, acc[tt][0], 0, 0, 0);
            acc[tt][1] = __builtin_amdgcn_mfma_f32_16x16x32_bf16(a, b1, acc[tt][1], 0, 0, 0);
        }
    }

    // D: out channel = lane&15 (+16 for acc1), pixel = xseg + tt*16 + (lane>>4)*4 + j
    const int prow = (lane >> 4) << 2;
    float* op0 = out + ((size_t)b * OO + (lane & 15)) * HW + (size_t)h * WW + xseg + prow;
#pragma unroll
    for (int tt = 0; tt < 8; ++tt) {
        __builtin_nontemporal_store(acc[tt][0], reinterpret_cast<f32x4*>(op0 + tt * 16));
        __builtin_nontemporal_store(acc[tt][1], reinterpret_cast<f32x4*>(op0 + tt * 16 + (size_t)16 * HW));
    }
}

// ---------------------------------------------------------------------------
extern "C" void kernel_launch(void* const* d_in, const int* in_sizes, int n_in,
                              void* d_out, int out_size, void* d_ws, size_t ws_size,
                              hipStream_t stream) {
    const float* x     = (const float*)d_in[0];
    const float* sigma = (const float*)d_in[1];
    const float* wgt   = (const float*)d_in[2];
    float* out = (float*)d_out;

    // ws layout: [ meta: 64 ints ][ wb2: 36*1024 bf16 ] (128 KB reserved)
    //            [ xbt: BB*HP*WP*CC bf16 padded image ]
    int* meta           = (int*)d_ws;
    unsigned short* wb2 = (unsigned short*)((char*)d_ws + 256);
    unsigned short* xbt = (unsigned short*)((char*)d_ws + 131072);

    wtrans_kernel<<<36, 256, 0, stream>>>(wgt, sigma, meta, wb2);
    blur_t_kernel<<<BB * 64, 256, 0, stream>>>(x, sigma, xbt);
    mix3_kernel<<<BB * 128, 256, 0, stream>>>(xbt, meta, wb2, out);
}